// Round 5
// baseline (291.620 us; speedup 1.0000x reference)
//
#include <hip/hip_runtime.h>
#include <stdint.h>

// MHA: x[2,2048,1024] fp32, mask[2,1,2048,2048] i32, Wq/k/v/o[1024,1024], b*[1024]
// H=16 heads, Hd=64. All GEMMs via mfma_f32_16x16x32_f16 (fp32 accum).
// R2: W pre-transposed f16 [n][k]; BK=64; fixed-max exp2 softmax.
// R5: swapped-QK attention (S^T = mfma(K,Q)) -> P is lane-local per q-row:
//     1 mask load + 4 packed P writes per tile (was 8 + 32 scalar);
//     qblk 64, grid 1024 (4 blocks/CU, was 2); V^T fused into k_qkv epilogue.

typedef _Float16 h8 __attribute__((ext_vector_type(8)));
typedef _Float16 h4 __attribute__((ext_vector_type(4)));
typedef float f32x4 __attribute__((ext_vector_type(4)));

#define MFMA16(a, b, c) __builtin_amdgcn_mfma_f32_16x16x32_f16(a, b, c, 0, 0, 0)

// XOR swizzle for 128B rows; touches byte-addr bits 4..6 only (preserves
// 16/8/2B alignment), bijective per row.
static __device__ __forceinline__ int swz128(int row, int colB) {
    return (row * 128 + colB) ^ ((row & 7) << 4);
}

// ---------------------------------------------------------------- mask pack
__global__ __launch_bounds__(256) void k_pack_mask(const int* __restrict__ mask,
                                                   uint32_t* __restrict__ mp) {
    int i = blockIdx.x * 256 + threadIdx.x;
    unsigned long long b = __ballot(mask[i] != 0);
    if ((threadIdx.x & 63) == 0) {
        *(unsigned long long*)(mp + (i >> 5)) = b;
    }
}

// ---------------------------------------------------------------- W transpose
// W[k][n] fp32 -> out[n][k] f16, 1024x1024, 64x64 tiles.
__global__ __launch_bounds__(256) void k_wt(const float* __restrict__ W0,
                                            const float* __restrict__ W1,
                                            const float* __restrict__ W2,
                                            _Float16* __restrict__ out) {
    const int nb = blockIdx.x, kb = blockIdx.y, z = blockIdx.z;
    const float* W = (z == 0) ? W0 : ((z == 1) ? W1 : W2);
    _Float16* O = out + (size_t)z * 1024 * 1024;
    __shared__ __align__(16) _Float16 lds[64][68];
    const int t = threadIdx.x;
    const int k0 = kb * 64, n0 = nb * 64;
#pragma unroll
    for (int p = 0; p < 4; ++p) {
        int idx = t + p * 256;
        int kr = idx >> 4;
        int c = idx & 15;
        float4 v = *(const float4*)(W + (size_t)(k0 + kr) * 1024 + n0 + c * 4);
        h4 hv;
        hv[0] = (_Float16)v.x; hv[1] = (_Float16)v.y;
        hv[2] = (_Float16)v.z; hv[3] = (_Float16)v.w;
        *(h4*)(&lds[kr][c * 4]) = hv;
    }
    __syncthreads();
#pragma unroll
    for (int p = 0; p < 2; ++p) {
        int idx = t + p * 256;
        int n = idx >> 3;
        int kc = idx & 7;
        h8 o;
#pragma unroll
        for (int i = 0; i < 8; ++i) o[i] = lds[kc * 8 + i][n];
        *(h8*)(O + (size_t)(n0 + n) * 1024 + k0 + kc * 8) = o;
    }
}

// ---------------------------------------------------------------- QKV GEMM
// 128x128 tile, BK=64, 4 waves 2x2. z==2 (V) writes transposed [nh][d][s].
__global__ __launch_bounds__(256) void k_qkv(const float* __restrict__ X,
                                             const _Float16* __restrict__ Wt,
                                             const float* __restrict__ bq,
                                             const float* __restrict__ bk,
                                             const float* __restrict__ bv,
                                             _Float16* __restrict__ Qo,
                                             _Float16* __restrict__ Ko,
                                             _Float16* __restrict__ VtO) {
    const int nt = blockIdx.x;
    const int mt = blockIdx.y;
    const int z = blockIdx.z;
    const _Float16* W = Wt + (size_t)z * 1024 * 1024;
    const float* bias = (z == 0) ? bq : ((z == 1) ? bk : bv);

    __shared__ __align__(16) char lds[32768];
    char* As = lds;
    char* Bs = lds + 16384;

    const int t = threadIdx.x;
    const int lane = t & 63;
    const int w = t >> 6;
    const int wm = w >> 1, wn = w & 1;
    const int m0 = mt * 128, n0 = nt * 128;

    f32x4 acc[4][4] = {};

    for (int kt = 0; kt < 16; ++kt) {
        const int k0 = kt * 64;
#pragma unroll
        for (int p = 0; p < 8; ++p) {
            int idx = t + p * 256;
            int row = idx >> 4;
            int c4 = idx & 15;
            float4 v = *(const float4*)(X + (size_t)(m0 + row) * 1024 + k0 + c4 * 4);
            h4 hv;
            hv[0] = (_Float16)v.x; hv[1] = (_Float16)v.y;
            hv[2] = (_Float16)v.z; hv[3] = (_Float16)v.w;
            *(h4*)(As + swz128(row, c4 * 8)) = hv;
        }
#pragma unroll
        for (int p = 0; p < 4; ++p) {
            int idx = t + p * 256;
            int row = idx >> 3;
            int c = idx & 7;
            uint4 v = *(const uint4*)(W + (size_t)(n0 + row) * 1024 + k0 + c * 8);
            *(uint4*)(Bs + swz128(row, c * 16)) = v;
        }
        __syncthreads();

#pragma unroll
        for (int kk = 0; kk < 2; ++kk) {
            h8 af[4], bf[4];
#pragma unroll
            for (int fm = 0; fm < 4; ++fm)
                af[fm] = *(h8*)(As + swz128(wm * 64 + fm * 16 + (lane & 15),
                                            kk * 64 + (lane >> 4) * 16));
#pragma unroll
            for (int fn = 0; fn < 4; ++fn)
                bf[fn] = *(h8*)(Bs + swz128(wn * 64 + fn * 16 + (lane & 15),
                                            kk * 64 + (lane >> 4) * 16));
#pragma unroll
            for (int fm = 0; fm < 4; ++fm)
#pragma unroll
                for (int fn = 0; fn < 4; ++fn)
                    acc[fm][fn] = MFMA16(af[fm], bf[fn], acc[fm][fn]);
        }
        __syncthreads();
    }

    // epilogue: D row=(lane>>4)*4+r, col=lane&15
    if (z == 2) {
        // V -> Vt[nh][d][s]; r is s-contiguous -> packed h4 writes
#pragma unroll
        for (int fn = 0; fn < 4; ++fn) {
            int n = n0 + wn * 64 + fn * 16 + (lane & 15);
            float bv_ = bias[n];
            int h = n >> 6, d = n & 63;
#pragma unroll
            for (int fm = 0; fm < 4; ++fm) {
                int m_base = m0 + wm * 64 + fm * 16 + (lane >> 4) * 4;
                int bi = m_base >> 11, s0 = m_base & 2047;
                h4 pv;
#pragma unroll
                for (int r = 0; r < 4; ++r) pv[r] = (_Float16)(acc[fm][fn][r] + bv_);
                *(h4*)(VtO + ((size_t)((bi * 16 + h) * 64 + d)) * 2048 + s0) = pv;
            }
        }
    } else {
        _Float16* Out = (z == 0) ? Qo : Ko;
#pragma unroll
        for (int fn = 0; fn < 4; ++fn) {
            int n = n0 + wn * 64 + fn * 16 + (lane & 15);
            float bv_ = bias[n];
            int h = n >> 6, d = n & 63;
#pragma unroll
            for (int fm = 0; fm < 4; ++fm) {
#pragma unroll
                for (int r = 0; r < 4; ++r) {
                    int m = m0 + wm * 64 + fm * 16 + (lane >> 4) * 4 + r;
                    int bi = m >> 11, s = m & 2047;
                    float val = acc[fm][fn][r] + bv_;
                    Out[(size_t)((bi * 16 + h) * 2048 + s) * 64 + d] = (_Float16)val;
                }
            }
        }
    }
}

// ---------------------------------------------------------------- attention
// 64 q-rows/block (4 waves x 16), grid (32,32) -> 4 blocks/CU.
// Swapped QK: S^T = mfma(K_frag, Q_frag) => thread holds q = lane&15,
// c = kt*64 + fn*16 + (lane>>4)*4 + r. Fixed-max exp2 softmax, lane-local l.
__global__ __launch_bounds__(256) void k_attn(const _Float16* __restrict__ Q,
                                              const _Float16* __restrict__ K,
                                              const _Float16* __restrict__ Vt,
                                              const uint32_t* __restrict__ mp,
                                              _Float16* __restrict__ ctx) {
    const int qt = blockIdx.x;  // 0..31
    const int nh = blockIdx.y;  // 0..31
    const int bi = nh >> 4;
    const int t = threadIdx.x, lane = t & 63, w = t >> 6;
    const int g = lane >> 4;    // 16-lane group 0..3
    const int q15 = lane & 15;

    __shared__ __align__(16) char lds[24576];
    char* Ks = lds;                      // [64 c][64 d] f16 swz
    char* Vs = lds + 8192;               // [64 d][64 c] f16 swz
    char* Ps = lds + 16384 + w * 2048;   // per-wave P [16 q][64 c] f16 swz

    const int qbase = qt * 64 + w * 16;

    // Q B-frag: col=lane&15 -> q-row, k=d = kk*32 + g*8 + j (contiguous)
    h8 qf[2];
#pragma unroll
    for (int kk = 0; kk < 2; ++kk)
        qf[kk] = *(const h8*)(Q + ((size_t)nh * 2048 + qbase + q15) * 64 + kk * 32 + g * 8);

    f32x4 of[4] = {};  // O[q=g*4+r][d=fn*16+q15] (D-layout)
    float lacc = 0.f;  // partial l for q = q15 over this thread's c-subset

    const size_t kbase = (size_t)nh * 2048 * 64;
    const size_t vbase = (size_t)nh * 64 * 2048;
    const float C1 = 0.18033688f;  // log2e / 8
    const float C2 = 11.541560f;   // 8 * log2e

    for (int kt = 0; kt < 32; ++kt) {
        // stage K tile [64c][64d] and Vt tile [64d][64c]
#pragma unroll
        for (int p = 0; p < 2; ++p) {
            int c = t + p * 256;  // 16B chunk id 0..511
            int row = c >> 3;
            int cb = (c & 7) * 16;
            uint4 kv = *(const uint4*)(K + kbase + (size_t)kt * 4096 + c * 8);
            *(uint4*)(Ks + swz128(row, cb)) = kv;
            uint4 vv = *(const uint4*)(Vt + vbase + (size_t)row * 2048 + kt * 64 + (c & 7) * 8);
            *(uint4*)(Vs + swz128(row, cb)) = vv;
        }
        __syncthreads();

        // S^T[c][q]: A = K (row c=fn*16+q15, k=d), B = Q^T
        f32x4 sf[4];
#pragma unroll
        for (int fn = 0; fn < 4; ++fn) {
            f32x4 a = {};
#pragma unroll
            for (int kk = 0; kk < 2; ++kk) {
                h8 kf = *(h8*)(Ks + swz128(fn * 16 + q15, kk * 64 + g * 16));
                a = MFMA16(kf, qf[kk], a);
            }
            sf[fn] = a;  // sf[fn][r]: q=q15, c = kt*64 + fn*16 + g*4 + r
        }

        // mask + exp2 + packed P write + lane-local l
        {
            uint2 mw = *(const uint2*)(mp + ((size_t)bi * 2048 + qbase + q15) * 64 + kt * 2);
#pragma unroll
            for (int fn = 0; fn < 4; ++fn) {
                uint32_t word = (fn & 2) ? mw.y : mw.x;
                int bitbase = ((fn & 1) << 4) + g * 4;
                h4 pv4;
#pragma unroll
                for (int r = 0; r < 4; ++r) {
                    float p = ((word >> (bitbase + r)) & 1u)
                                  ? __builtin_amdgcn_exp2f(fmaf(sf[fn][r], C1, -C2))
                                  : 0.f;
                    lacc += p;
                    pv4[r] = (_Float16)p;
                }
                *(h4*)(Ps + swz128(q15, (fn * 16 + g * 4) * 2)) = pv4;
            }
        }

        // O += P V : A-frag pa row=q15 (intra-wave LDS dep, no barrier)
        h8 pa[2];
#pragma unroll
        for (int kk = 0; kk < 2; ++kk)
            pa[kk] = *(h8*)(Ps + swz128(q15, kk * 64 + g * 16));
#pragma unroll
        for (int fn = 0; fn < 4; ++fn) {
#pragma unroll
            for (int kk = 0; kk < 2; ++kk) {
                h8 vb = *(h8*)(Vs + swz128(fn * 16 + q15, kk * 64 + g * 16));
                of[fn] = MFMA16(pa[kk], vb, of[fn]);
            }
        }
        __syncthreads();
    }

    // full l per q=q15: sum the 4 c-subsets (groups g)
    lacc += __shfl_xor(lacc, 16);
    lacc += __shfl_xor(lacc, 32);

    // epilogue: of row q_local = g*4+r needs l[q_local] -> shfl from lane q_local
#pragma unroll
    for (int r = 0; r < 4; ++r) {
        float lq = __shfl(lacc, g * 4 + r);
        int srow = qbase + g * 4 + r;
#pragma unroll
        for (int fn = 0; fn < 4; ++fn) {
            float val = of[fn][r] / lq;
            ctx[(size_t)(bi * 2048 + srow) * 1024 + (nh & 15) * 64 + fn * 16 + q15] =
                (_Float16)val;
        }
    }
}

// ---------------------------------------------------------------- O projection
__global__ __launch_bounds__(256) void k_oproj(const _Float16* __restrict__ A,
                                               const _Float16* __restrict__ Wot,
                                               const float* __restrict__ bias,
                                               float* __restrict__ out) {
    const int nt = blockIdx.x, mt = blockIdx.y;
    __shared__ __align__(16) char lds[32768];
    char* As = lds;
    char* Bs = lds + 16384;
    const int t = threadIdx.x, lane = t & 63, w = t >> 6;
    const int wm = w >> 1, wn = w & 1;
    const int m0 = mt * 128, n0 = nt * 128;
    f32x4 acc[4][4] = {};

    for (int kt = 0; kt < 16; ++kt) {
        const int k0 = kt * 64;
#pragma unroll
        for (int p = 0; p < 4; ++p) {
            int idx = t + p * 256;
            int row = idx >> 3;
            int c = idx & 7;
            uint4 v = *(const uint4*)(A + (size_t)(m0 + row) * 1024 + k0 + c * 8);
            *(uint4*)(As + swz128(row, c * 16)) = v;
        }
#pragma unroll
        for (int p = 0; p < 4; ++p) {
            int idx = t + p * 256;
            int row = idx >> 3;
            int c = idx & 7;
            uint4 v = *(const uint4*)(Wot + (size_t)(n0 + row) * 1024 + k0 + c * 8);
            *(uint4*)(Bs + swz128(row, c * 16)) = v;
        }
        __syncthreads();

#pragma unroll
        for (int kk = 0; kk < 2; ++kk) {
            h8 af[4], bf[4];
#pragma unroll
            for (int fm = 0; fm < 4; ++fm)
                af[fm] = *(h8*)(As + swz128(wm * 64 + fm * 16 + (lane & 15),
                                            kk * 64 + (lane >> 4) * 16));
#pragma unroll
            for (int fn = 0; fn < 4; ++fn)
                bf[fn] = *(h8*)(Bs + swz128(wn * 64 + fn * 16 + (lane & 15),
                                            kk * 64 + (lane >> 4) * 16));
#pragma unroll
            for (int fm = 0; fm < 4; ++fm)
#pragma unroll
                for (int fn = 0; fn < 4; ++fn)
                    acc[fm][fn] = MFMA16(af[fm], bf[fn], acc[fm][fn]);
        }
        __syncthreads();
    }

#pragma unroll
    for (int fn = 0; fn < 4; ++fn) {
        int n = n0 + wn * 64 + fn * 16 + (lane & 15);
        float b = bias[n];
#pragma unroll
        for (int fm = 0; fm < 4; ++fm) {
#pragma unroll
            for (int r = 0; r < 4; ++r) {
                int m = m0 + wm * 64 + fm * 16 + (lane >> 4) * 4 + r;
                out[(size_t)m * 1024 + n] = acc[fm][fn][r] + b;
            }
        }
    }
}

// ---------------------------------------------------------------- launch
extern "C" void kernel_launch(void* const* d_in, const int* in_sizes, int n_in,
                              void* d_out, int out_size, void* d_ws, size_t ws_size,
                              hipStream_t stream) {
    const float* x = (const float*)d_in[0];
    const int* mask = (const int*)d_in[1];
    const float* Wq = (const float*)d_in[2];
    const float* bq = (const float*)d_in[3];
    const float* Wk = (const float*)d_in[4];
    const float* bk = (const float*)d_in[5];
    const float* Wv = (const float*)d_in[6];
    const float* bv = (const float*)d_in[7];
    const float* Wo = (const float*)d_in[8];
    const float* bo = (const float*)d_in[9];
    float* out = (float*)d_out;

    // ws plan (33 MB, proven footprint). Stream-ordered lifetimes:
    //  [0,6M)   Wt (qkv weights f16^T)  -- dead after k_qkv
    //  [0,8M)   ctx                     -- written by k_attn (after Wt dead)
    //  [8,16M)  Q    [16,24M) K
    //  [24,32M) Vt (written by k_qkv)   -- dead after k_attn, then Wot [24,26M)
    //  [32,33M) mp
    char* ws = (char*)d_ws;
    _Float16* Wt = (_Float16*)(ws);
    _Float16* ctx = (_Float16*)(ws);
    _Float16* Q = (_Float16*)(ws + (8u << 20));
    _Float16* Kb = (_Float16*)(ws + (16u << 20));
    _Float16* Vt = (_Float16*)(ws + (24u << 20));
    _Float16* Wot = (_Float16*)(ws + (24u << 20));
    uint32_t* mp = (uint32_t*)(ws + (32u << 20));

    k_pack_mask<<<(2 * 2048 * 2048) / 256, 256, 0, stream>>>(mask, mp);
    k_wt<<<dim3(16, 16, 3), 256, 0, stream>>>(Wq, Wk, Wv, Wt);
    k_qkv<<<dim3(8, 32, 3), 256, 0, stream>>>(x, Wt, bq, bk, bv, Q, Kb, Vt);
    k_attn<<<dim3(32, 32), 256, 0, stream>>>(Q, Kb, Vt, mp, ctx);
    k_wt<<<dim3(16, 16, 1), 256, 0, stream>>>(Wo, Wo, Wo, Wot);
    k_oproj<<<dim3(8, 32), 256, 0, stream>>>(ctx, Wot, bo, out);
}

// Round 6
// 279.576 us; speedup vs baseline: 1.0431x; 1.0431x over previous
//
#include <hip/hip_runtime.h>
#include <stdint.h>

// MHA: x[2,2048,1024] fp32, mask[2,1,2048,2048] i32, Wq/k/v/o[1024,1024], b*[1024]
// H=16 heads, Hd=64. All GEMMs via mfma_f32_16x16x32_f16 (fp32 accum).
// R2: W pre-transposed f16 [n][k]; BK=64; fixed-max exp2 softmax.
// R5: swapped-QK attention; qblk 64, grid 1024; V^T fused into k_qkv.
// R6: X pre-converted to f16 (ws_size-gated, fp32 fallback); z==2 epilogue
//     writes Vt via 32KB LDS transpose (coalesced, was 8B scatter).

typedef _Float16 h8 __attribute__((ext_vector_type(8)));
typedef _Float16 h4 __attribute__((ext_vector_type(4)));
typedef float f32x4 __attribute__((ext_vector_type(4)));

#define MFMA16(a, b, c) __builtin_amdgcn_mfma_f32_16x16x32_f16(a, b, c, 0, 0, 0)

// XOR swizzle for 128B rows; touches byte-addr bits 4..6 only (preserves
// 16/8/2B alignment), bijective per row.
static __device__ __forceinline__ int swz128(int row, int colB) {
    return (row * 128 + colB) ^ ((row & 7) << 4);
}
// 256B rows (z==2 epilogue transpose): XOR bits 4..7.
static __device__ __forceinline__ int swz256(int row, int colB) {
    return (row * 256 + colB) ^ ((row & 15) << 4);
}

// ---------------------------------------------------------------- mask pack
__global__ __launch_bounds__(256) void k_pack_mask(const int* __restrict__ mask,
                                                   uint32_t* __restrict__ mp) {
    int i = blockIdx.x * 256 + threadIdx.x;
    unsigned long long b = __ballot(mask[i] != 0);
    if ((threadIdx.x & 63) == 0) {
        *(unsigned long long*)(mp + (i >> 5)) = b;
    }
}

// ---------------------------------------------------------------- X -> f16
__global__ __launch_bounds__(256) void k_xh(const float* __restrict__ X,
                                            _Float16* __restrict__ Xh) {
    int i = (blockIdx.x * 256 + threadIdx.x) * 8;
    float4 a = *(const float4*)(X + i);
    float4 b = *(const float4*)(X + i + 4);
    h8 o;
    o[0] = (_Float16)a.x; o[1] = (_Float16)a.y; o[2] = (_Float16)a.z; o[3] = (_Float16)a.w;
    o[4] = (_Float16)b.x; o[5] = (_Float16)b.y; o[6] = (_Float16)b.z; o[7] = (_Float16)b.w;
    *(h8*)(Xh + i) = o;
}

// ---------------------------------------------------------------- W transpose
// W[k][n] fp32 -> out[n][k] f16, 1024x1024, 64x64 tiles.
__global__ __launch_bounds__(256) void k_wt(const float* __restrict__ W0,
                                            const float* __restrict__ W1,
                                            const float* __restrict__ W2,
                                            _Float16* __restrict__ out) {
    const int nb = blockIdx.x, kb = blockIdx.y, z = blockIdx.z;
    const float* W = (z == 0) ? W0 : ((z == 1) ? W1 : W2);
    _Float16* O = out + (size_t)z * 1024 * 1024;
    __shared__ __align__(16) _Float16 lds[64][68];
    const int t = threadIdx.x;
    const int k0 = kb * 64, n0 = nb * 64;
#pragma unroll
    for (int p = 0; p < 4; ++p) {
        int idx = t + p * 256;
        int kr = idx >> 4;
        int c = idx & 15;
        float4 v = *(const float4*)(W + (size_t)(k0 + kr) * 1024 + n0 + c * 4);
        h4 hv;
        hv[0] = (_Float16)v.x; hv[1] = (_Float16)v.y;
        hv[2] = (_Float16)v.z; hv[3] = (_Float16)v.w;
        *(h4*)(&lds[kr][c * 4]) = hv;
    }
    __syncthreads();
#pragma unroll
    for (int p = 0; p < 2; ++p) {
        int idx = t + p * 256;
        int n = idx >> 3;
        int kc = idx & 7;
        h8 o;
#pragma unroll
        for (int i = 0; i < 8; ++i) o[i] = lds[kc * 8 + i][n];
        *(h8*)(O + (size_t)(n0 + n) * 1024 + k0 + kc * 8) = o;
    }
}

// ---------------------------------------------------------------- QKV GEMM
// 128x128 tile, BK=64, 4 waves 2x2. z==2 (V) -> Vt[nh][d][s] via LDS transpose.
__global__ __launch_bounds__(256) void k_qkv(const _Float16* __restrict__ Xh,
                                             const float* __restrict__ Xf,
                                             const int use_xh,
                                             const _Float16* __restrict__ Wt,
                                             const float* __restrict__ bq,
                                             const float* __restrict__ bk,
                                             const float* __restrict__ bv,
                                             _Float16* __restrict__ Qo,
                                             _Float16* __restrict__ Ko,
                                             _Float16* __restrict__ VtO) {
    const int nt = blockIdx.x;
    const int mt = blockIdx.y;
    const int z = blockIdx.z;
    const _Float16* W = Wt + (size_t)z * 1024 * 1024;
    const float* bias = (z == 0) ? bq : ((z == 1) ? bk : bv);

    __shared__ __align__(16) char lds[32768];
    char* As = lds;
    char* Bs = lds + 16384;

    const int t = threadIdx.x;
    const int lane = t & 63;
    const int w = t >> 6;
    const int wm = w >> 1, wn = w & 1;
    const int m0 = mt * 128, n0 = nt * 128;

    f32x4 acc[4][4] = {};

    for (int kt = 0; kt < 16; ++kt) {
        const int k0 = kt * 64;
        if (use_xh) {
            // A from f16 Xh: 128 rows x 64 f16, pure uint4 staging
#pragma unroll
            for (int p = 0; p < 4; ++p) {
                int idx = t + p * 256;
                int row = idx >> 3;
                int c = idx & 7;
                uint4 v = *(const uint4*)(Xh + (size_t)(m0 + row) * 1024 + k0 + c * 8);
                *(uint4*)(As + swz128(row, c * 16)) = v;
            }
        } else {
            // fallback: A from fp32 X, convert in-flight
#pragma unroll
            for (int p = 0; p < 8; ++p) {
                int idx = t + p * 256;
                int row = idx >> 4;
                int c4 = idx & 15;
                float4 v = *(const float4*)(Xf + (size_t)(m0 + row) * 1024 + k0 + c4 * 4);
                h4 hv;
                hv[0] = (_Float16)v.x; hv[1] = (_Float16)v.y;
                hv[2] = (_Float16)v.z; hv[3] = (_Float16)v.w;
                *(h4*)(As + swz128(row, c4 * 8)) = hv;
            }
        }
#pragma unroll
        for (int p = 0; p < 4; ++p) {
            int idx = t + p * 256;
            int row = idx >> 3;
            int c = idx & 7;
            uint4 v = *(const uint4*)(W + (size_t)(n0 + row) * 1024 + k0 + c * 8);
            *(uint4*)(Bs + swz128(row, c * 16)) = v;
        }
        __syncthreads();

#pragma unroll
        for (int kk = 0; kk < 2; ++kk) {
            h8 af[4], bf[4];
#pragma unroll
            for (int fm = 0; fm < 4; ++fm)
                af[fm] = *(h8*)(As + swz128(wm * 64 + fm * 16 + (lane & 15),
                                            kk * 64 + (lane >> 4) * 16));
#pragma unroll
            for (int fn = 0; fn < 4; ++fn)
                bf[fn] = *(h8*)(Bs + swz128(wn * 64 + fn * 16 + (lane & 15),
                                            kk * 64 + (lane >> 4) * 16));
#pragma unroll
            for (int fm = 0; fm < 4; ++fm)
#pragma unroll
                for (int fn = 0; fn < 4; ++fn)
                    acc[fm][fn] = MFMA16(af[fm], bf[fn], acc[fm][fn]);
        }
        __syncthreads();
    }

    // epilogue: D row=(lane>>4)*4+r, col=lane&15
    if (z == 2) {
        // V -> Vt[nh][d][s] coalesced, via full-LDS [n_local 128][m_local 128]
        // f16 transpose buffer (swizzled 256B rows).
        const int bi = m0 >> 11, s0 = m0 & 2047;
#pragma unroll
        for (int fn = 0; fn < 4; ++fn) {
            int n_local = wn * 64 + fn * 16 + (lane & 15);
            float bv_ = bias[n0 + n_local];
#pragma unroll
            for (int fm = 0; fm < 4; ++fm) {
                int m_base = wm * 64 + fm * 16 + (lane >> 4) * 4;
                h4 pv;
#pragma unroll
                for (int r = 0; r < 4; ++r) pv[r] = (_Float16)(acc[fm][fn][r] + bv_);
                *(h4*)(lds + swz256(n_local, m_base * 2)) = pv;
            }
        }
        __syncthreads();
#pragma unroll
        for (int p = 0; p < 8; ++p) {
            int idx = t + p * 256;   // 0..2047 uint4 chunks
            int row = idx >> 4;      // n_local 0..127
            int c16 = idx & 15;      // 16B col
            uint4 v = *(uint4*)(lds + swz256(row, c16 * 16));
            int hg = (n0 >> 6) + (row >> 6);
            int d = row & 63;
            *(uint4*)(VtO + ((size_t)((bi * 16 + hg) * 64 + d)) * 2048 + s0 + c16 * 8) = v;
        }
    } else {
        _Float16* Out = (z == 0) ? Qo : Ko;
#pragma unroll
        for (int fn = 0; fn < 4; ++fn) {
            int n = n0 + wn * 64 + fn * 16 + (lane & 15);
            float bv_ = bias[n];
            int h = n >> 6, d = n & 63;
#pragma unroll
            for (int fm = 0; fm < 4; ++fm) {
#pragma unroll
                for (int r = 0; r < 4; ++r) {
                    int m = m0 + wm * 64 + fm * 16 + (lane >> 4) * 4 + r;
                    int bi = m >> 11, s = m & 2047;
                    float val = acc[fm][fn][r] + bv_;
                    Out[(size_t)((bi * 16 + h) * 2048 + s) * 64 + d] = (_Float16)val;
                }
            }
        }
    }
}

// ---------------------------------------------------------------- attention
// 64 q-rows/block (4 waves x 16), grid (32,32) -> 4 blocks/CU.
// Swapped QK: S^T = mfma(K_frag, Q_frag) => thread holds q = lane&15,
// c = kt*64 + fn*16 + (lane>>4)*4 + r. Fixed-max exp2 softmax, lane-local l.
__global__ __launch_bounds__(256) void k_attn(const _Float16* __restrict__ Q,
                                              const _Float16* __restrict__ K,
                                              const _Float16* __restrict__ Vt,
                                              const uint32_t* __restrict__ mp,
                                              _Float16* __restrict__ ctx) {
    const int qt = blockIdx.x;  // 0..31
    const int nh = blockIdx.y;  // 0..31
    const int bi = nh >> 4;
    const int t = threadIdx.x, lane = t & 63, w = t >> 6;
    const int g = lane >> 4;    // 16-lane group 0..3
    const int q15 = lane & 15;

    __shared__ __align__(16) char lds[24576];
    char* Ks = lds;                      // [64 c][64 d] f16 swz
    char* Vs = lds + 8192;               // [64 d][64 c] f16 swz
    char* Ps = lds + 16384 + w * 2048;   // per-wave P [16 q][64 c] f16 swz

    const int qbase = qt * 64 + w * 16;

    // Q B-frag: col=lane&15 -> q-row, k=d = kk*32 + g*8 + j (contiguous)
    h8 qf[2];
#pragma unroll
    for (int kk = 0; kk < 2; ++kk)
        qf[kk] = *(const h8*)(Q + ((size_t)nh * 2048 + qbase + q15) * 64 + kk * 32 + g * 8);

    f32x4 of[4] = {};  // O[q=g*4+r][d=fn*16+q15] (D-layout)
    float lacc = 0.f;  // partial l for q = q15 over this thread's c-subset

    const size_t kbase = (size_t)nh * 2048 * 64;
    const size_t vbase = (size_t)nh * 64 * 2048;
    const float C1 = 0.18033688f;  // log2e / 8
    const float C2 = 11.541560f;   // 8 * log2e

    for (int kt = 0; kt < 32; ++kt) {
        // stage K tile [64c][64d] and Vt tile [64d][64c]
#pragma unroll
        for (int p = 0; p < 2; ++p) {
            int c = t + p * 256;  // 16B chunk id 0..511
            int row = c >> 3;
            int cb = (c & 7) * 16;
            uint4 kv = *(const uint4*)(K + kbase + (size_t)kt * 4096 + c * 8);
            *(uint4*)(Ks + swz128(row, cb)) = kv;
            uint4 vv = *(const uint4*)(Vt + vbase + (size_t)row * 2048 + kt * 64 + (c & 7) * 8);
            *(uint4*)(Vs + swz128(row, cb)) = vv;
        }
        __syncthreads();

        // S^T[c][q]: A = K (row c=fn*16+q15, k=d), B = Q^T
        f32x4 sf[4];
#pragma unroll
        for (int fn = 0; fn < 4; ++fn) {
            f32x4 a = {};
#pragma unroll
            for (int kk = 0; kk < 2; ++kk) {
                h8 kf = *(h8*)(Ks + swz128(fn * 16 + q15, kk * 64 + g * 16));
                a = MFMA16(kf, qf[kk], a);
            }
            sf[fn] = a;  // sf[fn][r]: q=q15, c = kt*64 + fn*16 + g*4 + r
        }

        // mask + exp2 + packed P write + lane-local l
        {
            uint2 mw = *(const uint2*)(mp + ((size_t)bi * 2048 + qbase + q15) * 64 + kt * 2);
#pragma unroll
            for (int fn = 0; fn < 4; ++fn) {
                uint32_t word = (fn & 2) ? mw.y : mw.x;
                int bitbase = ((fn & 1) << 4) + g * 4;
                h4 pv4;
#pragma unroll
                for (int r = 0; r < 4; ++r) {
                    float p = ((word >> (bitbase + r)) & 1u)
                                  ? __builtin_amdgcn_exp2f(fmaf(sf[fn][r], C1, -C2))
                                  : 0.f;
                    lacc += p;
                    pv4[r] = (_Float16)p;
                }
                *(h4*)(Ps + swz128(q15, (fn * 16 + g * 4) * 2)) = pv4;
            }
        }

        // O += P V : A-frag pa row=q15 (intra-wave LDS dep, no barrier)
        h8 pa[2];
#pragma unroll
        for (int kk = 0; kk < 2; ++kk)
            pa[kk] = *(h8*)(Ps + swz128(q15, kk * 64 + g * 16));
#pragma unroll
        for (int fn = 0; fn < 4; ++fn) {
#pragma unroll
            for (int kk = 0; kk < 2; ++kk) {
                h8 vb = *(h8*)(Vs + swz128(fn * 16 + q15, kk * 64 + g * 16));
                of[fn] = MFMA16(pa[kk], vb, of[fn]);
            }
        }
        __syncthreads();
    }

    // full l per q=q15: sum the 4 c-subsets (groups g)
    lacc += __shfl_xor(lacc, 16);
    lacc += __shfl_xor(lacc, 32);

    // epilogue: of row q_local = g*4+r needs l[q_local] -> shfl from lane q_local
#pragma unroll
    for (int r = 0; r < 4; ++r) {
        float lq = __shfl(lacc, g * 4 + r);
        int srow = qbase + g * 4 + r;
#pragma unroll
        for (int fn = 0; fn < 4; ++fn) {
            float val = of[fn][r] / lq;
            ctx[(size_t)(bi * 2048 + srow) * 1024 + (nh & 15) * 64 + fn * 16 + q15] =
                (_Float16)val;
        }
    }
}

// ---------------------------------------------------------------- O projection
__global__ __launch_bounds__(256) void k_oproj(const _Float16* __restrict__ A,
                                               const _Float16* __restrict__ Wot,
                                               const float* __restrict__ bias,
                                               float* __restrict__ out) {
    const int nt = blockIdx.x, mt = blockIdx.y;
    __shared__ __align__(16) char lds[32768];
    char* As = lds;
    char* Bs = lds + 16384;
    const int t = threadIdx.x, lane = t & 63, w = t >> 6;
    const int wm = w >> 1, wn = w & 1;
    const int m0 = mt * 128, n0 = nt * 128;
    f32x4 acc[4][4] = {};

    for (int kt = 0; kt < 16; ++kt) {
        const int k0 = kt * 64;
#pragma unroll
        for (int p = 0; p < 4; ++p) {
            int idx = t + p * 256;
            int row = idx >> 3;
            int c = idx & 7;
            uint4 v = *(const uint4*)(A + (size_t)(m0 + row) * 1024 + k0 + c * 8);
            *(uint4*)(As + swz128(row, c * 16)) = v;
        }
#pragma unroll
        for (int p = 0; p < 4; ++p) {
            int idx = t + p * 256;
            int row = idx >> 3;
            int c = idx & 7;
            uint4 v = *(const uint4*)(Wot + (size_t)(n0 + row) * 1024 + k0 + c * 8);
            *(uint4*)(Bs + swz128(row, c * 16)) = v;
        }
        __syncthreads();

#pragma unroll
        for (int kk = 0; kk < 2; ++kk) {
            h8 af[4], bf[4];
#pragma unroll
            for (int fm = 0; fm < 4; ++fm)
                af[fm] = *(h8*)(As + swz128(wm * 64 + fm * 16 + (lane & 15),
                                            kk * 64 + (lane >> 4) * 16));
#pragma unroll
            for (int fn = 0; fn < 4; ++fn)
                bf[fn] = *(h8*)(Bs + swz128(wn * 64 + fn * 16 + (lane & 15),
                                            kk * 64 + (lane >> 4) * 16));
#pragma unroll
            for (int fm = 0; fm < 4; ++fm)
#pragma unroll
                for (int fn = 0; fn < 4; ++fn)
                    acc[fm][fn] = MFMA16(af[fm], bf[fn], acc[fm][fn]);
        }
        __syncthreads();
    }

#pragma unroll
    for (int fn = 0; fn < 4; ++fn) {
        int n = n0 + wn * 64 + fn * 16 + (lane & 15);
        float b = bias[n];
#pragma unroll
        for (int fm = 0; fm < 4; ++fm) {
#pragma unroll
            for (int r = 0; r < 4; ++r) {
                int m = m0 + wm * 64 + fm * 16 + (lane >> 4) * 4 + r;
                out[(size_t)m * 1024 + n] = acc[fm][fn][r] + b;
            }
        }
    }
}

// ---------------------------------------------------------------- launch
extern "C" void kernel_launch(void* const* d_in, const int* in_sizes, int n_in,
                              void* d_out, int out_size, void* d_ws, size_t ws_size,
                              hipStream_t stream) {
    const float* x = (const float*)d_in[0];
    const int* mask = (const int*)d_in[1];
    const float* Wq = (const float*)d_in[2];
    const float* bq = (const float*)d_in[3];
    const float* Wk = (const float*)d_in[4];
    const float* bk = (const float*)d_in[5];
    const float* Wv = (const float*)d_in[6];
    const float* bv = (const float*)d_in[7];
    const float* Wo = (const float*)d_in[8];
    const float* bo = (const float*)d_in[9];
    float* out = (float*)d_out;

    // ws plan:
    //  [0,6M)   Wt (qkv weights f16^T)  -- dead after k_qkv
    //  [0,8M)   ctx                     -- written by k_attn (after Wt dead)
    //  [8,16M)  Q    [16,24M) K
    //  [24,32M) Vt (written by k_qkv)   -- dead after k_attn, then Wot [24,26M)
    //  [32,33M) mp
    //  [33,41M) Xh (f16 X)              -- only if ws_size >= 41M
    char* ws = (char*)d_ws;
    _Float16* Wt = (_Float16*)(ws);
    _Float16* ctx = (_Float16*)(ws);
    _Float16* Q = (_Float16*)(ws + (8u << 20));
    _Float16* Kb = (_Float16*)(ws + (16u << 20));
    _Float16* Vt = (_Float16*)(ws + (24u << 20));
    _Float16* Wot = (_Float16*)(ws + (24u << 20));
    uint32_t* mp = (uint32_t*)(ws + (32u << 20));
    _Float16* Xh = (_Float16*)(ws + (33u << 20));
    const int use_xh = (ws_size >= (41u << 20)) ? 1 : 0;

    k_pack_mask<<<(2 * 2048 * 2048) / 256, 256, 0, stream>>>(mask, mp);
    k_wt<<<dim3(16, 16, 3), 256, 0, stream>>>(Wq, Wk, Wv, Wt);
    if (use_xh) {
        k_xh<<<(2 * 2048 * 1024) / (256 * 8), 256, 0, stream>>>(x, Xh);
    }
    k_qkv<<<dim3(8, 32, 3), 256, 0, stream>>>(Xh, x, use_xh, Wt, bq, bk, bv, Q, Kb, Vt);
    k_attn<<<dim3(32, 32), 256, 0, stream>>>(Q, Kb, Vt, mp, ctx);
    k_wt<<<dim3(16, 16, 1), 256, 0, stream>>>(Wo, Wo, Wo, Wot);
    k_oproj<<<dim3(8, 32), 256, 0, stream>>>(ctx, Wot, bo, out);
}

// Round 7
// 268.210 us; speedup vs baseline: 1.0873x; 1.0424x over previous
//
#include <hip/hip_runtime.h>
#include <stdint.h>

// MHA: x[2,2048,1024] fp32, mask[2,1,2048,2048] i32, Wq/k/v/o[1024,1024], b*[1024]
// H=16 heads, Hd=64. All GEMMs via mfma_f32_16x16x32_f16 (fp32 accum).
// R2: W pre-transposed f16 [n][k]; BK=64; fixed-max exp2 softmax.
// R5: swapped-QK attention; V^T fused into k_qkv.
// R6: X pre-converted to f16 (ws-gated); Vt epilogue via LDS transpose.
// R7: attn 32 q-rows/wave (K/V frag reads amortized 2x — LDS pipe was the
//     binding resource at ~82% of iter time). Grid (16,32).

typedef _Float16 h8 __attribute__((ext_vector_type(8)));
typedef _Float16 h4 __attribute__((ext_vector_type(4)));
typedef float f32x4 __attribute__((ext_vector_type(4)));

#define MFMA16(a, b, c) __builtin_amdgcn_mfma_f32_16x16x32_f16(a, b, c, 0, 0, 0)

// XOR swizzle for 128B rows; touches byte-addr bits 4..6 only (preserves
// 16/8/2B alignment), bijective per row.
static __device__ __forceinline__ int swz128(int row, int colB) {
    return (row * 128 + colB) ^ ((row & 7) << 4);
}
// 256B rows (z==2 epilogue transpose): XOR bits 4..7.
static __device__ __forceinline__ int swz256(int row, int colB) {
    return (row * 256 + colB) ^ ((row & 15) << 4);
}

// ---------------------------------------------------------------- mask pack
__global__ __launch_bounds__(256) void k_pack_mask(const int* __restrict__ mask,
                                                   uint32_t* __restrict__ mp) {
    int i = blockIdx.x * 256 + threadIdx.x;
    unsigned long long b = __ballot(mask[i] != 0);
    if ((threadIdx.x & 63) == 0) {
        *(unsigned long long*)(mp + (i >> 5)) = b;
    }
}

// ---------------------------------------------------------------- X -> f16
__global__ __launch_bounds__(256) void k_xh(const float* __restrict__ X,
                                            _Float16* __restrict__ Xh) {
    int i = (blockIdx.x * 256 + threadIdx.x) * 8;
    float4 a = *(const float4*)(X + i);
    float4 b = *(const float4*)(X + i + 4);
    h8 o;
    o[0] = (_Float16)a.x; o[1] = (_Float16)a.y; o[2] = (_Float16)a.z; o[3] = (_Float16)a.w;
    o[4] = (_Float16)b.x; o[5] = (_Float16)b.y; o[6] = (_Float16)b.z; o[7] = (_Float16)b.w;
    *(h8*)(Xh + i) = o;
}

// ---------------------------------------------------------------- W transpose
// W[k][n] fp32 -> out[n][k] f16, 1024x1024, 64x64 tiles.
__global__ __launch_bounds__(256) void k_wt(const float* __restrict__ W0,
                                            const float* __restrict__ W1,
                                            const float* __restrict__ W2,
                                            _Float16* __restrict__ out) {
    const int nb = blockIdx.x, kb = blockIdx.y, z = blockIdx.z;
    const float* W = (z == 0) ? W0 : ((z == 1) ? W1 : W2);
    _Float16* O = out + (size_t)z * 1024 * 1024;
    __shared__ __align__(16) _Float16 lds[64][68];
    const int t = threadIdx.x;
    const int k0 = kb * 64, n0 = nb * 64;
#pragma unroll
    for (int p = 0; p < 4; ++p) {
        int idx = t + p * 256;
        int kr = idx >> 4;
        int c = idx & 15;
        float4 v = *(const float4*)(W + (size_t)(k0 + kr) * 1024 + n0 + c * 4);
        h4 hv;
        hv[0] = (_Float16)v.x; hv[1] = (_Float16)v.y;
        hv[2] = (_Float16)v.z; hv[3] = (_Float16)v.w;
        *(h4*)(&lds[kr][c * 4]) = hv;
    }
    __syncthreads();
#pragma unroll
    for (int p = 0; p < 2; ++p) {
        int idx = t + p * 256;
        int n = idx >> 3;
        int kc = idx & 7;
        h8 o;
#pragma unroll
        for (int i = 0; i < 8; ++i) o[i] = lds[kc * 8 + i][n];
        *(h8*)(O + (size_t)(n0 + n) * 1024 + k0 + kc * 8) = o;
    }
}

// ---------------------------------------------------------------- QKV GEMM
// 128x128 tile, BK=64, 4 waves 2x2. z==2 (V) -> Vt[nh][d][s] via LDS transpose.
__global__ __launch_bounds__(256) void k_qkv(const _Float16* __restrict__ Xh,
                                             const float* __restrict__ Xf,
                                             const int use_xh,
                                             const _Float16* __restrict__ Wt,
                                             const float* __restrict__ bq,
                                             const float* __restrict__ bk,
                                             const float* __restrict__ bv,
                                             _Float16* __restrict__ Qo,
                                             _Float16* __restrict__ Ko,
                                             _Float16* __restrict__ VtO) {
    const int nt = blockIdx.x;
    const int mt = blockIdx.y;
    const int z = blockIdx.z;
    const _Float16* W = Wt + (size_t)z * 1024 * 1024;
    const float* bias = (z == 0) ? bq : ((z == 1) ? bk : bv);

    __shared__ __align__(16) char lds[32768];
    char* As = lds;
    char* Bs = lds + 16384;

    const int t = threadIdx.x;
    const int lane = t & 63;
    const int w = t >> 6;
    const int wm = w >> 1, wn = w & 1;
    const int m0 = mt * 128, n0 = nt * 128;

    f32x4 acc[4][4] = {};

    for (int kt = 0; kt < 16; ++kt) {
        const int k0 = kt * 64;
        if (use_xh) {
            // A from f16 Xh: 128 rows x 64 f16, pure uint4 staging
#pragma unroll
            for (int p = 0; p < 4; ++p) {
                int idx = t + p * 256;
                int row = idx >> 3;
                int c = idx & 7;
                uint4 v = *(const uint4*)(Xh + (size_t)(m0 + row) * 1024 + k0 + c * 8);
                *(uint4*)(As + swz128(row, c * 16)) = v;
            }
        } else {
            // fallback: A from fp32 X, convert in-flight
#pragma unroll
            for (int p = 0; p < 8; ++p) {
                int idx = t + p * 256;
                int row = idx >> 4;
                int c4 = idx & 15;
                float4 v = *(const float4*)(Xf + (size_t)(m0 + row) * 1024 + k0 + c4 * 4);
                h4 hv;
                hv[0] = (_Float16)v.x; hv[1] = (_Float16)v.y;
                hv[2] = (_Float16)v.z; hv[3] = (_Float16)v.w;
                *(h4*)(As + swz128(row, c4 * 8)) = hv;
            }
        }
#pragma unroll
        for (int p = 0; p < 4; ++p) {
            int idx = t + p * 256;
            int row = idx >> 3;
            int c = idx & 7;
            uint4 v = *(const uint4*)(W + (size_t)(n0 + row) * 1024 + k0 + c * 8);
            *(uint4*)(Bs + swz128(row, c * 16)) = v;
        }
        __syncthreads();

#pragma unroll
        for (int kk = 0; kk < 2; ++kk) {
            h8 af[4], bf[4];
#pragma unroll
            for (int fm = 0; fm < 4; ++fm)
                af[fm] = *(h8*)(As + swz128(wm * 64 + fm * 16 + (lane & 15),
                                            kk * 64 + (lane >> 4) * 16));
#pragma unroll
            for (int fn = 0; fn < 4; ++fn)
                bf[fn] = *(h8*)(Bs + swz128(wn * 64 + fn * 16 + (lane & 15),
                                            kk * 64 + (lane >> 4) * 16));
#pragma unroll
            for (int fm = 0; fm < 4; ++fm)
#pragma unroll
                for (int fn = 0; fn < 4; ++fn)
                    acc[fm][fn] = MFMA16(af[fm], bf[fn], acc[fm][fn]);
        }
        __syncthreads();
    }

    // epilogue: D row=(lane>>4)*4+r, col=lane&15
    if (z == 2) {
        // V -> Vt[nh][d][s] coalesced, via full-LDS [n_local 128][m_local 128]
        // f16 transpose buffer (swizzled 256B rows).
        const int bi = m0 >> 11, s0 = m0 & 2047;
#pragma unroll
        for (int fn = 0; fn < 4; ++fn) {
            int n_local = wn * 64 + fn * 16 + (lane & 15);
            float bv_ = bias[n0 + n_local];
#pragma unroll
            for (int fm = 0; fm < 4; ++fm) {
                int m_base = wm * 64 + fm * 16 + (lane >> 4) * 4;
                h4 pv;
#pragma unroll
                for (int r = 0; r < 4; ++r) pv[r] = (_Float16)(acc[fm][fn][r] + bv_);
                *(h4*)(lds + swz256(n_local, m_base * 2)) = pv;
            }
        }
        __syncthreads();
#pragma unroll
        for (int p = 0; p < 8; ++p) {
            int idx = t + p * 256;   // 0..2047 uint4 chunks
            int row = idx >> 4;      // n_local 0..127
            int c16 = idx & 15;      // 16B col
            uint4 v = *(uint4*)(lds + swz256(row, c16 * 16));
            int hg = (n0 >> 6) + (row >> 6);
            int d = row & 63;
            *(uint4*)(VtO + ((size_t)((bi * 16 + hg) * 64 + d)) * 2048 + s0 + c16 * 8) = v;
        }
    } else {
        _Float16* Out = (z == 0) ? Qo : Ko;
#pragma unroll
        for (int fn = 0; fn < 4; ++fn) {
            int n = n0 + wn * 64 + fn * 16 + (lane & 15);
            float bv_ = bias[n];
            int h = n >> 6, d = n & 63;
#pragma unroll
            for (int fm = 0; fm < 4; ++fm) {
#pragma unroll
                for (int r = 0; r < 4; ++r) {
                    int m = m0 + wm * 64 + fm * 16 + (lane >> 4) * 4 + r;
                    int bi = m >> 11, s = m & 2047;
                    float val = acc[fm][fn][r] + bv_;
                    Out[(size_t)((bi * 16 + h) * 2048 + s) * 64 + d] = (_Float16)val;
                }
            }
        }
    }
}

// ---------------------------------------------------------------- attention
// 128 q-rows/block, 4 waves x 32 q-rows each; grid (16,32) = 512 blocks.
// Swapped QK: S^T = mfma(K_frag, Q_frag). Each K/V frag read from LDS feeds
// TWO q-half MFMAs (2x LDS amortization vs R5). Fixed-max exp2 softmax.
__global__ __launch_bounds__(256) void k_attn(const _Float16* __restrict__ Q,
                                              const _Float16* __restrict__ K,
                                              const _Float16* __restrict__ Vt,
                                              const uint32_t* __restrict__ mp,
                                              _Float16* __restrict__ ctx) {
    const int qt = blockIdx.x;  // 0..15
    const int nh = blockIdx.y;  // 0..31
    const int bi = nh >> 4;
    const int t = threadIdx.x, lane = t & 63, w = t >> 6;
    const int g = lane >> 4;    // 16-lane group 0..3
    const int q15 = lane & 15;

    __shared__ __align__(16) char lds[32768];
    char* Ks = lds;                      // [64 c][64 d] f16 swz
    char* Vs = lds + 8192;               // [64 d][64 c] f16 swz
    char* Ps = lds + 16384 + w * 4096;   // per-wave P [32 q][64 c] f16 swz

    const int qbase = qt * 128 + w * 32;

    // Q B-frags: col=lane&15 -> q-row, k=d = kk*32 + g*8 + j (contiguous)
    h8 qf[2][2];
#pragma unroll
    for (int qh = 0; qh < 2; ++qh)
#pragma unroll
        for (int kk = 0; kk < 2; ++kk)
            qf[qh][kk] = *(const h8*)(Q + ((size_t)nh * 2048 + qbase + qh * 16 + q15) * 64 +
                                      kk * 32 + g * 8);

    f32x4 of[2][4] = {};   // O[q = qh*16 + g*4 + r][d = fn*16 + q15]
    float lacc[2] = {};    // partial l for q-rows (qbase+qh*16+q15)

    const size_t kbase = (size_t)nh * 2048 * 64;
    const size_t vbase = (size_t)nh * 64 * 2048;
    const float C1 = 0.18033688f;  // log2e / 8
    const float C2 = 11.541560f;   // 8 * log2e

    for (int kt = 0; kt < 32; ++kt) {
        // stage K tile [64c][64d] and Vt tile [64d][64c]
#pragma unroll
        for (int p = 0; p < 2; ++p) {
            int c = t + p * 256;  // 16B chunk id 0..511
            int row = c >> 3;
            int cb = (c & 7) * 16;
            uint4 kv = *(const uint4*)(K + kbase + (size_t)kt * 4096 + c * 8);
            *(uint4*)(Ks + swz128(row, cb)) = kv;
            uint4 vv = *(const uint4*)(Vt + vbase + (size_t)row * 2048 + kt * 64 + (c & 7) * 8);
            *(uint4*)(Vs + swz128(row, cb)) = vv;
        }
        __syncthreads();

        // S^T[c][q]: A = K (row c=fn*16+q15, k=d), B = Q^T; each kf feeds 2 qh
        f32x4 sf[2][4];
#pragma unroll
        for (int fn = 0; fn < 4; ++fn) {
            f32x4 a0 = {}, a1 = {};
#pragma unroll
            for (int kk = 0; kk < 2; ++kk) {
                h8 kf = *(h8*)(Ks + swz128(fn * 16 + q15, kk * 64 + g * 16));
                a0 = MFMA16(kf, qf[0][kk], a0);
                a1 = MFMA16(kf, qf[1][kk], a1);
            }
            sf[0][fn] = a0;  // q=q15 (qh=0), c = kt*64 + fn*16 + g*4 + r
            sf[1][fn] = a1;  // q=16+q15 (qh=1)
        }

        // mask + exp2 + packed P write + lane-local l
#pragma unroll
        for (int qh = 0; qh < 2; ++qh) {
            uint2 mw =
                *(const uint2*)(mp + ((size_t)bi * 2048 + qbase + qh * 16 + q15) * 64 + kt * 2);
#pragma unroll
            for (int fn = 0; fn < 4; ++fn) {
                uint32_t word = (fn & 2) ? mw.y : mw.x;
                int bitbase = ((fn & 1) << 4) + g * 4;
                h4 pv4;
#pragma unroll
                for (int r = 0; r < 4; ++r) {
                    float p = ((word >> (bitbase + r)) & 1u)
                                  ? __builtin_amdgcn_exp2f(fmaf(sf[qh][fn][r], C1, -C2))
                                  : 0.f;
                    lacc[qh] += p;
                    pv4[r] = (_Float16)p;
                }
                *(h4*)(Ps + swz128(qh * 16 + q15, (fn * 16 + g * 4) * 2)) = pv4;
            }
        }

        // O += P V : each vb feeds 2 qh (intra-wave LDS dep, no barrier)
        h8 pa[2][2];
#pragma unroll
        for (int qh = 0; qh < 2; ++qh)
#pragma unroll
            for (int kk = 0; kk < 2; ++kk)
                pa[qh][kk] = *(h8*)(Ps + swz128(qh * 16 + q15, kk * 64 + g * 16));
#pragma unroll
        for (int fn = 0; fn < 4; ++fn) {
#pragma unroll
            for (int kk = 0; kk < 2; ++kk) {
                h8 vb = *(h8*)(Vs + swz128(fn * 16 + q15, kk * 64 + g * 16));
                of[0][fn] = MFMA16(pa[0][kk], vb, of[0][fn]);
                of[1][fn] = MFMA16(pa[1][kk], vb, of[1][fn]);
            }
        }
        __syncthreads();
    }

    // full l per q-row: sum the 4 c-subsets (groups g)
#pragma unroll
    for (int qh = 0; qh < 2; ++qh) {
        lacc[qh] += __shfl_xor(lacc[qh], 16);
        lacc[qh] += __shfl_xor(lacc[qh], 32);
    }

    // epilogue: of[qh] row q_local = g*4+r needs l from lane q15 = g*4+r
#pragma unroll
    for (int qh = 0; qh < 2; ++qh) {
#pragma unroll
        for (int r = 0; r < 4; ++r) {
            float lq = __shfl(lacc[qh], g * 4 + r);
            int srow = qbase + qh * 16 + g * 4 + r;
#pragma unroll
            for (int fn = 0; fn < 4; ++fn) {
                float val = of[qh][fn][r] / lq;
                ctx[(size_t)(bi * 2048 + srow) * 1024 + (nh & 15) * 64 + fn * 16 + q15] =
                    (_Float16)val;
            }
        }
    }
}

// ---------------------------------------------------------------- O projection
__global__ __launch_bounds__(256) void k_oproj(const _Float16* __restrict__ A,
                                               const _Float16* __restrict__ Wot,
                                               const float* __restrict__ bias,
                                               float* __restrict__ out) {
    const int nt = blockIdx.x, mt = blockIdx.y;
    __shared__ __align__(16) char lds[32768];
    char* As = lds;
    char* Bs = lds + 16384;
    const int t = threadIdx.x, lane = t & 63, w = t >> 6;
    const int wm = w >> 1, wn = w & 1;
    const int m0 = mt * 128, n0 = nt * 128;
    f32x4 acc[4][4] = {};

    for (int kt = 0; kt < 16; ++kt) {
        const int k0 = kt * 64;
#pragma unroll
        for (int p = 0; p < 4; ++p) {
            int idx = t + p * 256;
            int row = idx >> 3;
            int c = idx & 7;
            uint4 v = *(const uint4*)(A + (size_t)(m0 + row) * 1024 + k0 + c * 8);
            *(uint4*)(As + swz128(row, c * 16)) = v;
        }
#pragma unroll
        for (int p = 0; p < 4; ++p) {
            int idx = t + p * 256;
            int row = idx >> 3;
            int c = idx & 7;
            uint4 v = *(const uint4*)(Wot + (size_t)(n0 + row) * 1024 + k0 + c * 8);
            *(uint4*)(Bs + swz128(row, c * 16)) = v;
        }
        __syncthreads();

#pragma unroll
        for (int kk = 0; kk < 2; ++kk) {
            h8 af[4], bf[4];
#pragma unroll
            for (int fm = 0; fm < 4; ++fm)
                af[fm] = *(h8*)(As + swz128(wm * 64 + fm * 16 + (lane & 15),
                                            kk * 64 + (lane >> 4) * 16));
#pragma unroll
            for (int fn = 0; fn < 4; ++fn)
                bf[fn] = *(h8*)(Bs + swz128(wn * 64 + fn * 16 + (lane & 15),
                                            kk * 64 + (lane >> 4) * 16));
#pragma unroll
            for (int fm = 0; fm < 4; ++fm)
#pragma unroll
                for (int fn = 0; fn < 4; ++fn)
                    acc[fm][fn] = MFMA16(af[fm], bf[fn], acc[fm][fn]);
        }
        __syncthreads();
    }

#pragma unroll
    for (int fn = 0; fn < 4; ++fn) {
        int n = n0 + wn * 64 + fn * 16 + (lane & 15);
        float b = bias[n];
#pragma unroll
        for (int fm = 0; fm < 4; ++fm) {
#pragma unroll
            for (int r = 0; r < 4; ++r) {
                int m = m0 + wm * 64 + fm * 16 + (lane >> 4) * 4 + r;
                out[(size_t)m * 1024 + n] = acc[fm][fn][r] + b;
            }
        }
    }
}

// ---------------------------------------------------------------- launch
extern "C" void kernel_launch(void* const* d_in, const int* in_sizes, int n_in,
                              void* d_out, int out_size, void* d_ws, size_t ws_size,
                              hipStream_t stream) {
    const float* x = (const float*)d_in[0];
    const int* mask = (const int*)d_in[1];
    const float* Wq = (const float*)d_in[2];
    const float* bq = (const float*)d_in[3];
    const float* Wk = (const float*)d_in[4];
    const float* bk = (const float*)d_in[5];
    const float* Wv = (const float*)d_in[6];
    const float* bv = (const float*)d_in[7];
    const float* Wo = (const float*)d_in[8];
    const float* bo = (const float*)d_in[9];
    float* out = (float*)d_out;

    // ws plan:
    //  [0,6M)   Wt (qkv weights f16^T)  -- dead after k_qkv
    //  [0,8M)   ctx                     -- written by k_attn (after Wt dead)
    //  [8,16M)  Q    [16,24M) K
    //  [24,32M) Vt (written by k_qkv)   -- dead after k_attn, then Wot [24,26M)
    //  [32,33M) mp
    //  [33,41M) Xh (f16 X)              -- only if ws_size >= 41M
    char* ws = (char*)d_ws;
    _Float16* Wt = (_Float16*)(ws);
    _Float16* ctx = (_Float16*)(ws);
    _Float16* Q = (_Float16*)(ws + (8u << 20));
    _Float16* Kb = (_Float16*)(ws + (16u << 20));
    _Float16* Vt = (_Float16*)(ws + (24u << 20));
    _Float16* Wot = (_Float16*)(ws + (24u << 20));
    uint32_t* mp = (uint32_t*)(ws + (32u << 20));
    _Float16* Xh = (_Float16*)(ws + (33u << 20));
    const int use_xh = (ws_size >= (41u << 20)) ? 1 : 0;

    k_pack_mask<<<(2 * 2048 * 2048) / 256, 256, 0, stream>>>(mask, mp);
    k_wt<<<dim3(16, 16, 3), 256, 0, stream>>>(Wq, Wk, Wv, Wt);
    if (use_xh) {
        k_xh<<<(2 * 2048 * 1024) / (256 * 8), 256, 0, stream>>>(x, Xh);
    }
    k_qkv<<<dim3(8, 32, 3), 256, 0, stream>>>(Xh, x, use_xh, Wt, bq, bk, bv, Q, Kb, Vt);
    k_attn<<<dim3(16, 32), 256, 0, stream>>>(Q, Kb, Vt, mp, ctx);
    k_wt<<<dim3(16, 16, 1), 256, 0, stream>>>(Wo, Wo, Wo, Wot);
    k_oproj<<<dim3(8, 32), 256, 0, stream>>>(ctx, Wot, bo, out);
}